// Round 2
// baseline (602.628 us; speedup 1.0000x reference)
//
#include <hip/hip_runtime.h>
#include <hip/hip_bf16.h>

// ---------------------------------------------------------------------------
// myGRUCell low-rank, split into 4 high-occupancy kernels (R2).
//
//   prep: pack weights bf16 transposed into ws
//   k1  : A12[B][128] = [x@W | h@U]  (bf16)          reads x,h (256 MB)
//   k2  : rhU[B][64]  = (sigmoid(pre_r) * h) @ U     reads h   (128 MB)
//   k3  : out = z*h + (1-z)*tanh(pre_c)              reads h (L3-hot), writes out
//
// ws layout (shorts):
//   [0       .. 65535  ] Wt  [64][1024]
//   [65536   .. 131071 ] Ut  [64][1024]
//   [131072  .. 262143 ] P1t [1024][128]  (k<64: W1, else U1)
//   [262144  .. 393215 ] P2t [1024][128]
//   [393216  .. 524287 ] P3t [1024][128]
//   [524288  .. 4718591] A12 [32768][128]
//   [4718592 .. 6815743] rhU [32768][64]
// ---------------------------------------------------------------------------

typedef __attribute__((ext_vector_type(8))) short short8;   // 8 x bf16
typedef __attribute__((ext_vector_type(4))) float f32x4;
typedef __attribute__((ext_vector_type(4))) float f4;

#define WS_UT   65536
#define WS_P1T  131072
#define WS_P2T  262144
#define WS_P3T  393216
#define WS_A12  524288
#define WS_RHU  4718592

__device__ __forceinline__ short f2bf(float f) {
  unsigned u = __builtin_bit_cast(unsigned, f);
  u += 0x7FFFu + ((u >> 16) & 1u);          // round-nearest-even
  return (short)(u >> 16);
}

__device__ __forceinline__ f32x4 mfma16(short8 a, short8 b, f32x4 c) {
  return __builtin_amdgcn_mfma_f32_16x16x32_bf16(a, b, c, 0, 0, 0);
}

// LDS tiles are [64 rows][128 k] bf16.  XOR-swizzle the 8-short granule with
// row&7 so 16-lane column reads spread over 8 bank slots (2-way = free).
__device__ __forceinline__ short8 lds_read_frag(const short* base, int row, int k) {
  return *reinterpret_cast<const short8*>(base + row * 128 + (k ^ ((row & 7) << 3)));
}
__device__ __forceinline__ void lds_write_elem(short* base, int row, int col, short v) {
  base[row * 128 + (col ^ ((row & 7) << 3))] = v;
}
__device__ __forceinline__ void lds_write_gran(short* base, int row, int col8, short8 v) {
  *reinterpret_cast<short8*>(base + row * 128 + (col8 ^ ((row & 7) << 3))) = v;
}

__device__ __forceinline__ float sigm_f(float v) { return 1.f / (1.f + __expf(-v)); }
__device__ __forceinline__ float tanh_f(float v) { return 1.f - 2.f / (__expf(2.f * v) + 1.f); }

// ---------------------------------------------------------------------------
__global__ void prep_kernel(const float* __restrict__ W,  const float* __restrict__ W1,
                            const float* __restrict__ W2, const float* __restrict__ W3,
                            const float* __restrict__ U,  const float* __restrict__ U1,
                            const float* __restrict__ U2, const float* __restrict__ U3,
                            short* __restrict__ ws) {
  int i = blockIdx.x * blockDim.x + threadIdx.x;  // 0 .. 524287
  float v;
  if (i < 65536) {
    int n = i >> 10, k = i & 1023;
    v = W[k * 64 + n];
  } else if (i < 131072) {
    int j = i - 65536;
    int n = j >> 10, k = j & 1023;
    v = U[k * 64 + n];
  } else {
    int j = i - 131072;
    int sel = j >> 17;          // 0,1,2
    int jj = j & 131071;
    int n = jj >> 7, k = jj & 127;
    const float* Wk = sel == 0 ? W1 : sel == 1 ? W2 : W3;
    const float* Uk = sel == 0 ? U1 : sel == 1 ? U2 : U3;
    v = (k < 64) ? Wk[k * 1024 + n] : Uk[(k - 64) * 1024 + n];
  }
  ws[i] = f2bf(v);
}

// ---------------------------------------------------------------------------
// k1: A12 = [x@W | h@U] bf16.  32 rows/block, 4 waves; wave pair splits K.
// grid = B/32 = 1024.
// ---------------------------------------------------------------------------
__global__ __launch_bounds__(256, 4) void k1_a12(
    const float* __restrict__ x, const float* __restrict__ h,
    const short* __restrict__ ws, short* __restrict__ A12) {
  const short* Wt = ws;
  const short* Ut = ws + WS_UT;
  __shared__ float sPart[2][8][16][17];   // [rowgrp][cf][row'][l15] (+pad)

  const int tid = threadIdx.x;
  const int w   = tid >> 6;
  const int l   = tid & 63;
  const int l15 = l & 15;
  const int lg  = l >> 4;
  const int g   = w >> 1;        // row group 0,1
  const int kh  = w & 1;         // K half
  const int r0  = blockIdx.x * 32;

  const int row = r0 + g * 16 + l15;
  const float* xrow = x + (size_t)row * 1024 + kh * 512;
  const float* hrow = h + (size_t)row * 1024 + kh * 512;
  const int kbase = kh * 512;

  f32x4 acc[8] = {};
#pragma unroll 2
  for (int k0 = 0; k0 < 512; k0 += 32) {
    const int koff = k0 + lg * 8;
    f4 xa = *reinterpret_cast<const f4*>(xrow + koff);
    f4 xb = *reinterpret_cast<const f4*>(xrow + koff + 4);
    f4 ha = *reinterpret_cast<const f4*>(hrow + koff);
    f4 hb = *reinterpret_cast<const f4*>(hrow + koff + 4);
    short8 ax, ah;
#pragma unroll
    for (int j = 0; j < 4; ++j) {
      ax[j] = f2bf(xa[j]); ax[4 + j] = f2bf(xb[j]);
      ah[j] = f2bf(ha[j]); ah[4 + j] = f2bf(hb[j]);
    }
    const int k = kbase + koff;
#pragma unroll
    for (int cf = 0; cf < 4; ++cf) {
      short8 bw = *reinterpret_cast<const short8*>(Wt + (cf * 16 + l15) * 1024 + k);
      acc[cf] = mfma16(ax, bw, acc[cf]);
    }
#pragma unroll
    for (int cf = 0; cf < 4; ++cf) {
      short8 bu = *reinterpret_cast<const short8*>(Ut + (cf * 16 + l15) * 1024 + k);
      acc[4 + cf] = mfma16(ah, bu, acc[4 + cf]);
    }
  }

  if (kh == 1) {
#pragma unroll
    for (int cf = 0; cf < 8; ++cf)
#pragma unroll
      for (int j = 0; j < 4; ++j)
        sPart[g][cf][lg * 4 + j][l15] = acc[cf][j];
  }
  __syncthreads();
  if (kh == 0) {
#pragma unroll
    for (int cf = 0; cf < 8; ++cf)
#pragma unroll
      for (int j = 0; j < 4; ++j) {
        float v = acc[cf][j] + sPart[g][cf][lg * 4 + j][l15];
        int rr = r0 + g * 16 + lg * 4 + j;
        A12[(size_t)rr * 128 + cf * 16 + l15] = f2bf(v);
      }
  }
}

// ---------------------------------------------------------------------------
// k2: rhU = (sigmoid(A12@P1 + h*U1d + bR) * h) @ U.   64 rows/block, grid 512.
// ---------------------------------------------------------------------------
__global__ __launch_bounds__(256, 4) void k2_rhu(
    const float* __restrict__ h, const float* __restrict__ u1d,
    const float* __restrict__ biasR,
    const short* __restrict__ ws, const short* __restrict__ A12,
    short* __restrict__ rhU) {
  const short* Ut  = ws + WS_UT;
  const short* P1t = ws + WS_P1T;

  __shared__ __align__(16) short sA [64 * 128];
  __shared__ __align__(16) short sRH[64 * 128];

  const int tid = threadIdx.x;
  const int w   = tid >> 6;
  const int l   = tid & 63;
  const int l15 = l & 15;
  const int lg  = l >> 4;
  const int r0  = blockIdx.x * 64;

  // stage A12 block tile into LDS (swizzled)
  for (int gidx = tid; gidx < 1024; gidx += 256) {
    int row = gidx >> 4, c8 = (gidx & 15) * 8;
    short8 v = *reinterpret_cast<const short8*>(A12 + (size_t)(r0 + row) * 128 + c8);
    lds_write_gran(sA, row, c8, v);
  }
  __syncthreads();

  const int wr = w >> 1;
  const int wc = w & 1;
  const int m0 = 32 * wr;

  f32x4 accU[4] = {};
  for (int t = 0; t < 8; ++t) {
    const int n0 = t * 128 + wc * 64;
    f32x4 accR[2][4] = {};
#pragma unroll
    for (int k0 = 0; k0 < 128; k0 += 32) {
      short8 a0 = lds_read_frag(sA, m0 + l15,      k0 + lg * 8);
      short8 a1 = lds_read_frag(sA, m0 + 16 + l15, k0 + lg * 8);
#pragma unroll
      for (int cf = 0; cf < 4; ++cf) {
        short8 b = *reinterpret_cast<const short8*>(P1t + (n0 + cf * 16 + l15) * 128 + k0 + lg * 8);
        accR[0][cf] = mfma16(a0, b, accR[0][cf]);
        accR[1][cf] = mfma16(a1, b, accR[1][cf]);
      }
    }
#pragma unroll
    for (int rf = 0; rf < 2; ++rf)
#pragma unroll
      for (int cf = 0; cf < 4; ++cf) {
        int cc = n0 + cf * 16 + l15;
        float d1 = u1d[cc], b_r = biasR[cc];
#pragma unroll
        for (int j = 0; j < 4; ++j) {
          int rr = m0 + rf * 16 + lg * 4 + j;
          float hv = h[(size_t)(r0 + rr) * 1024 + cc];
          float rv = sigm_f(accR[rf][cf][j] + hv * d1 + b_r);
          lds_write_elem(sRH, rr, cc - t * 128, f2bf(rv * hv));
        }
      }
    __syncthreads();
#pragma unroll
    for (int kk = 0; kk < 128; kk += 32) {
      short8 a = lds_read_frag(sRH, 16 * w + l15, kk + lg * 8);
#pragma unroll
      for (int cf = 0; cf < 4; ++cf) {
        short8 b = *reinterpret_cast<const short8*>(Ut + (cf * 16 + l15) * 1024 + t * 128 + kk + lg * 8);
        accU[cf] = mfma16(a, b, accU[cf]);
      }
    }
    __syncthreads();
  }

#pragma unroll
  for (int cf = 0; cf < 4; ++cf)
#pragma unroll
    for (int j = 0; j < 4; ++j) {
      int rr = r0 + 16 * w + lg * 4 + j;
      rhU[(size_t)rr * 64 + cf * 16 + l15] = f2bf(accU[cf][j]);
    }
}

// ---------------------------------------------------------------------------
// k3: out = z*h + (1-z)*tanh(pre_c).   64 rows/block, grid 512.
// ---------------------------------------------------------------------------
__global__ __launch_bounds__(256, 4) void k3_out(
    const float* __restrict__ h,
    const float* __restrict__ u1d, const float* __restrict__ u2d,
    const float* __restrict__ u3d,
    const float* __restrict__ biasR, const float* __restrict__ biasZ,
    const float* __restrict__ biasU,
    const short* __restrict__ ws, const short* __restrict__ A12,
    const short* __restrict__ rhU, float* __restrict__ out) {
  const short* P1t = ws + WS_P1T;
  const short* P2t = ws + WS_P2T;
  const short* P3t = ws + WS_P3T;

  __shared__ __align__(16) short sA12[64 * 128];
  __shared__ __align__(16) short sA3 [64 * 128];

  const int tid = threadIdx.x;
  const int w   = tid >> 6;
  const int l   = tid & 63;
  const int l15 = l & 15;
  const int lg  = l >> 4;
  const int r0  = blockIdx.x * 64;

  for (int gidx = tid; gidx < 1024; gidx += 256) {
    int row = gidx >> 4, c8 = (gidx & 15) * 8;
    short8 v = *reinterpret_cast<const short8*>(A12 + (size_t)(r0 + row) * 128 + c8);
    lds_write_gran(sA12, row, c8, v);
    short8 v3;
    if (c8 < 64) v3 = v;    // xW half
    else v3 = *reinterpret_cast<const short8*>(rhU + (size_t)(r0 + row) * 64 + (c8 - 64));
    lds_write_gran(sA3, row, c8, v3);
  }
  __syncthreads();

  const int wr = w >> 1;
  const int wc = w & 1;
  const int m0 = 32 * wr;

  for (int t = 0; t < 8; ++t) {
    const int n0 = t * 128 + wc * 64;
    f32x4 aR[2][4] = {}, aZ[2][4] = {}, aC[2][4] = {};
#pragma unroll
    for (int k0 = 0; k0 < 128; k0 += 32) {
      short8 a12_0 = lds_read_frag(sA12, m0 + l15,      k0 + lg * 8);
      short8 a12_1 = lds_read_frag(sA12, m0 + 16 + l15, k0 + lg * 8);
      short8 a3_0  = lds_read_frag(sA3,  m0 + l15,      k0 + lg * 8);
      short8 a3_1  = lds_read_frag(sA3,  m0 + 16 + l15, k0 + lg * 8);
#pragma unroll
      for (int cf = 0; cf < 4; ++cf) {
        int bo = (n0 + cf * 16 + l15) * 128 + k0 + lg * 8;
        short8 b1 = *reinterpret_cast<const short8*>(P1t + bo);
        short8 b2 = *reinterpret_cast<const short8*>(P2t + bo);
        short8 b3 = *reinterpret_cast<const short8*>(P3t + bo);
        aR[0][cf] = mfma16(a12_0, b1, aR[0][cf]);
        aR[1][cf] = mfma16(a12_1, b1, aR[1][cf]);
        aZ[0][cf] = mfma16(a12_0, b2, aZ[0][cf]);
        aZ[1][cf] = mfma16(a12_1, b2, aZ[1][cf]);
        aC[0][cf] = mfma16(a3_0,  b3, aC[0][cf]);
        aC[1][cf] = mfma16(a3_1,  b3, aC[1][cf]);
      }
    }
#pragma unroll
    for (int rf = 0; rf < 2; ++rf)
#pragma unroll
      for (int cf = 0; cf < 4; ++cf) {
        int cc = n0 + cf * 16 + l15;
        float d1 = u1d[cc], d2 = u2d[cc], d3 = u3d[cc];
        float b_r = biasR[cc], b_z = biasZ[cc], b_u = biasU[cc];
#pragma unroll
        for (int j = 0; j < 4; ++j) {
          int rr = m0 + rf * 16 + lg * 4 + j;
          size_t gi = (size_t)(r0 + rr) * 1024 + cc;
          float hv = h[gi];
          float rv = sigm_f(aR[rf][cf][j] + hv * d1 + b_r);
          float rhv = rv * hv;
          float zv = sigm_f(aZ[rf][cf][j] + hv * d2 + b_z);
          float cv = tanh_f(aC[rf][cf][j] + rhv * d3 + b_u);
          out[gi] = zv * hv + (1.f - zv) * cv;
        }
      }
  }
}

extern "C" void kernel_launch(void* const* d_in, const int* in_sizes, int n_in,
                              void* d_out, int out_size, void* d_ws, size_t ws_size,
                              hipStream_t stream) {
  const float* x   = (const float*)d_in[0];
  const float* h   = (const float*)d_in[1];
  const float* W   = (const float*)d_in[2];
  const float* W1  = (const float*)d_in[3];
  const float* W2  = (const float*)d_in[4];
  const float* W3  = (const float*)d_in[5];
  const float* U   = (const float*)d_in[6];
  const float* U1  = (const float*)d_in[7];
  const float* U2  = (const float*)d_in[8];
  const float* U3  = (const float*)d_in[9];
  const float* u1d = (const float*)d_in[10];
  const float* u2d = (const float*)d_in[11];
  const float* u3d = (const float*)d_in[12];
  const float* bR  = (const float*)d_in[13];
  const float* bZ  = (const float*)d_in[14];
  const float* bU  = (const float*)d_in[15];
  short* ws  = (short*)d_ws;
  short* A12 = ws + WS_A12;
  short* rhU = ws + WS_RHU;

  prep_kernel<<<2048, 256, 0, stream>>>(W, W1, W2, W3, U, U1, U2, U3, ws);
  k1_a12<<<1024, 256, 0, stream>>>(x, h, ws, A12);
  k2_rhu<<<512, 256, 0, stream>>>(h, u1d, bR, ws, A12, rhU);
  k3_out<<<512, 256, 0, stream>>>(h, u1d, u2d, u3d, bR, bZ, bU, ws, A12, rhU, (float*)d_out);
}

// Round 3
// 338.418 us; speedup vs baseline: 1.7807x; 1.7807x over previous
//
#include <hip/hip_runtime.h>
#include <hip/hip_bf16.h>

// ---------------------------------------------------------------------------
// myGRUCell low-rank fused monolith, R3.
//   grid 512 x 512 threads (8 waves) -> 2 blocks/CU, 16 waves/CU, one round.
//   sA[64][192] = [xW | hU | rhU] bf16 in LDS (no global round-trip).
//   Phase 0: no barriers (wave-private K-full GEMMs).
//   Phase 1: 1 barrier/tile (sRH double-buffered).
//   Phase 2: 0 barriers.
// ws: bf16 weights only:
//   [0      ..65535 ] Wt  [64][1024]
//   [65536  ..131071] Ut  [64][1024]
//   [131072 ..262143] P1t [1024][128] (k<64: W1, else U1)
//   [262144 ..393215] P2t [1024][128]
//   [393216 ..524287] P3t [1024][128]
// ---------------------------------------------------------------------------

typedef __attribute__((ext_vector_type(8))) short short8;   // 8 x bf16
typedef __attribute__((ext_vector_type(4))) float f32x4;
typedef __attribute__((ext_vector_type(4))) float f4;

#define WS_UT   65536
#define WS_P1T  131072
#define WS_P2T  262144
#define WS_P3T  393216

__device__ __forceinline__ short f2bf(float f) {
  unsigned u = __builtin_bit_cast(unsigned, f);
  u += 0x7FFFu + ((u >> 16) & 1u);          // round-nearest-even
  return (short)(u >> 16);
}

__device__ __forceinline__ short8 cvt8(f4 a, f4 b) {
  short8 r;
#pragma unroll
  for (int j = 0; j < 4; ++j) { r[j] = f2bf(a[j]); r[4 + j] = f2bf(b[j]); }
  return r;
}

__device__ __forceinline__ f32x4 mfma16(short8 a, short8 b, f32x4 c) {
  return __builtin_amdgcn_mfma_f32_16x16x32_bf16(a, b, c, 0, 0, 0);
}

// XOR-swizzled LDS tiles (16B granule x row&7): 16 rows / same col -> 2-way
// bank aliasing (free, m136).  Row strides are multiples of 128B so the
// granule-slot analysis is stride-independent.
__device__ __forceinline__ short8 rd192(const short* b, int row, int col) {
  return *reinterpret_cast<const short8*>(b + row * 192 + (col ^ ((row & 7) << 3)));
}
__device__ __forceinline__ void wr192(short* b, int row, int col, short v) {
  b[row * 192 + (col ^ ((row & 7) << 3))] = v;
}
__device__ __forceinline__ short8 rd128(const short* b, int row, int col) {
  return *reinterpret_cast<const short8*>(b + row * 128 + (col ^ ((row & 7) << 3)));
}
__device__ __forceinline__ void wr128(short* b, int row, int col, short v) {
  b[row * 128 + (col ^ ((row & 7) << 3))] = v;
}

__device__ __forceinline__ float sigm_f(float v) { return 1.f / (1.f + __expf(-v)); }
__device__ __forceinline__ float tanh_f(float v) { return 1.f - 2.f / (__expf(2.f * v) + 1.f); }

// ---------------------------------------------------------------------------
__global__ void prep_kernel(const float* __restrict__ W,  const float* __restrict__ W1,
                            const float* __restrict__ W2, const float* __restrict__ W3,
                            const float* __restrict__ U,  const float* __restrict__ U1,
                            const float* __restrict__ U2, const float* __restrict__ U3,
                            short* __restrict__ ws) {
  int i = blockIdx.x * blockDim.x + threadIdx.x;  // 0 .. 524287
  float v;
  if (i < 65536) {
    int n = i >> 10, k = i & 1023;
    v = W[k * 64 + n];
  } else if (i < 131072) {
    int j = i - 65536;
    int n = j >> 10, k = j & 1023;
    v = U[k * 64 + n];
  } else {
    int j = i - 131072;
    int sel = j >> 17;          // 0,1,2
    int jj = j & 131071;
    int n = jj >> 7, k = jj & 127;
    const float* Wk = sel == 0 ? W1 : sel == 1 ? W2 : W3;
    const float* Uk = sel == 0 ? U1 : sel == 1 ? U2 : U3;
    v = (k < 64) ? Wk[k * 1024 + n] : Uk[(k - 64) * 1024 + n];
  }
  ws[i] = f2bf(v);
}

// ---------------------------------------------------------------------------
__global__ __launch_bounds__(512, 4) void gru_fused(
    const float* __restrict__ x, const float* __restrict__ h,
    const float* __restrict__ u1d, const float* __restrict__ u2d,
    const float* __restrict__ u3d,
    const float* __restrict__ biasR, const float* __restrict__ biasZ,
    const float* __restrict__ biasU,
    const short* __restrict__ ws, float* __restrict__ out) {
  const short* Wt  = ws;
  const short* Ut  = ws + WS_UT;
  const short* P1t = ws + WS_P1T;
  const short* P2t = ws + WS_P2T;
  const short* P3t = ws + WS_P3T;

  __shared__ __align__(16) short sA[64 * 192];       // [xW | hU | rhU]
  __shared__ __align__(16) short sRH[2][64 * 128];   // rh col-tile, dbuf

  const int tid = threadIdx.x;
  const int w   = tid >> 6;      // wave 0..7
  const int l   = tid & 63;
  const int l15 = l & 15;
  const int lg  = l >> 4;
  const int r0  = blockIdx.x * 64;

  // ---- Phase 0 (no barriers): wave w: rows 16*(w&3); w<4 -> xW, w>=4 -> hU
  {
    const int g = w & 3;
    const int m = w >> 2;
    const float* srow = (m ? h : x) + (size_t)(r0 + 16 * g + l15) * 1024;
    const short* Bt   = m ? Ut : Wt;
    f32x4 acc[4] = {};
#pragma unroll 2
    for (int k0 = 0; k0 < 1024; k0 += 32) {
      const int koff = k0 + lg * 8;
      f4 a = *reinterpret_cast<const f4*>(srow + koff);
      f4 b = *reinterpret_cast<const f4*>(srow + koff + 4);
      short8 av = cvt8(a, b);
#pragma unroll
      for (int cf = 0; cf < 4; ++cf) {
        short8 bw = *reinterpret_cast<const short8*>(Bt + (cf * 16 + l15) * 1024 + koff);
        acc[cf] = mfma16(av, bw, acc[cf]);
      }
    }
#pragma unroll
    for (int cf = 0; cf < 4; ++cf)
#pragma unroll
      for (int j = 0; j < 4; ++j)
        wr192(sA, 16 * g + lg * 4 + j, m * 64 + cf * 16 + l15, f2bf(acc[cf][j]));
  }
  __syncthreads();

  const int wr = w >> 2;          // 0,1 : 32-row half
  const int wc = w & 3;           // 0..3: 32-col quarter of the 128-tile
  const int m0 = 32 * wr;
  const int wq = w & 3;           // accU row group
  const int wh = w >> 2;          // accU col half

  // ---- Phase 1: r -> rh -> rhU accumulation.  1 barrier per tile.
  f32x4 accU[2] = {};
  for (int t = 0; t < 8; ++t) {
    const int n0 = t * 128 + wc * 32;
    f32x4 accR[2][2] = {};
#pragma unroll
    for (int k0 = 0; k0 < 128; k0 += 32) {
      short8 a0 = rd192(sA, m0 + l15,      k0 + lg * 8);
      short8 a1 = rd192(sA, m0 + 16 + l15, k0 + lg * 8);
#pragma unroll
      for (int cf = 0; cf < 2; ++cf) {
        short8 b = *reinterpret_cast<const short8*>(P1t + (n0 + cf * 16 + l15) * 128 + k0 + lg * 8);
        accR[0][cf] = mfma16(a0, b, accR[0][cf]);
        accR[1][cf] = mfma16(a1, b, accR[1][cf]);
      }
    }
    short* rhbuf = &sRH[t & 1][0];
#pragma unroll
    for (int rf = 0; rf < 2; ++rf)
#pragma unroll
      for (int cf = 0; cf < 2; ++cf) {
        int cc = n0 + cf * 16 + l15;
        float d1 = u1d[cc], b_r = biasR[cc];
        float hv[4];
#pragma unroll
        for (int j = 0; j < 4; ++j)
          hv[j] = h[(size_t)(r0 + m0 + rf * 16 + lg * 4 + j) * 1024 + cc];
#pragma unroll
        for (int j = 0; j < 4; ++j) {
          int rr = m0 + rf * 16 + lg * 4 + j;
          float rv = sigm_f(accR[rf][cf][j] + hv[j] * d1 + b_r);
          wr128(rhbuf, rr, cc - t * 128, f2bf(rv * hv[j]));
        }
      }
    __syncthreads();
#pragma unroll
    for (int kk = 0; kk < 128; kk += 32) {
      short8 a = rd128(rhbuf, 16 * wq + l15, kk + lg * 8);
#pragma unroll
      for (int cf = 0; cf < 2; ++cf) {
        short8 b = *reinterpret_cast<const short8*>(Ut + (wh * 32 + cf * 16 + l15) * 1024 + t * 128 + kk + lg * 8);
        accU[cf] = mfma16(a, b, accU[cf]);
      }
    }
  }
  // rhU -> sA cols 128..191
#pragma unroll
  for (int cf = 0; cf < 2; ++cf)
#pragma unroll
    for (int j = 0; j < 4; ++j)
      wr192(sA, 16 * wq + lg * 4 + j, 128 + wh * 32 + cf * 16 + l15, f2bf(accU[cf][j]));
  __syncthreads();

  // ---- Phase 2 (no barriers): recompute r,z; c; gate; store.
  for (int t = 0; t < 8; ++t) {
    const int n0 = t * 128 + wc * 32;
    f32x4 aR[2][2] = {}, aZ[2][2] = {}, aC[2][2] = {};
#pragma unroll
    for (int k0 = 0; k0 < 128; k0 += 32) {
      short8 a12_0 = rd192(sA, m0 + l15,      k0 + lg * 8);
      short8 a12_1 = rd192(sA, m0 + 16 + l15, k0 + lg * 8);
      short8 a3_0, a3_1;
      if (k0 < 64) { a3_0 = a12_0; a3_1 = a12_1; }
      else {
        a3_0 = rd192(sA, m0 + l15,      64 + k0 + lg * 8);   // 128 + (k0-64)
        a3_1 = rd192(sA, m0 + 16 + l15, 64 + k0 + lg * 8);
      }
#pragma unroll
      for (int cf = 0; cf < 2; ++cf) {
        int bo = (n0 + cf * 16 + l15) * 128 + k0 + lg * 8;
        short8 b1 = *reinterpret_cast<const short8*>(P1t + bo);
        short8 b2 = *reinterpret_cast<const short8*>(P2t + bo);
        short8 b3 = *reinterpret_cast<const short8*>(P3t + bo);
        aR[0][cf] = mfma16(a12_0, b1, aR[0][cf]);
        aR[1][cf] = mfma16(a12_1, b1, aR[1][cf]);
        aZ[0][cf] = mfma16(a12_0, b2, aZ[0][cf]);
        aZ[1][cf] = mfma16(a12_1, b2, aZ[1][cf]);
        aC[0][cf] = mfma16(a3_0,  b3, aC[0][cf]);
        aC[1][cf] = mfma16(a3_1,  b3, aC[1][cf]);
      }
    }
#pragma unroll
    for (int rf = 0; rf < 2; ++rf)
#pragma unroll
      for (int cf = 0; cf < 2; ++cf) {
        int cc = n0 + cf * 16 + l15;
        float d1 = u1d[cc], d2 = u2d[cc], d3 = u3d[cc];
        float b_r = biasR[cc], b_z = biasZ[cc], b_u = biasU[cc];
        float hv[4];
#pragma unroll
        for (int j = 0; j < 4; ++j)
          hv[j] = h[(size_t)(r0 + m0 + rf * 16 + lg * 4 + j) * 1024 + cc];
#pragma unroll
        for (int j = 0; j < 4; ++j) {
          int rr = m0 + rf * 16 + lg * 4 + j;
          size_t gi = (size_t)(r0 + rr) * 1024 + cc;
          float rv = sigm_f(aR[rf][cf][j] + hv[j] * d1 + b_r);
          float zv = sigm_f(aZ[rf][cf][j] + hv[j] * d2 + b_z);
          float cv = tanh_f(aC[rf][cf][j] + rv * hv[j] * d3 + b_u);
          out[gi] = zv * hv[j] + (1.f - zv) * cv;
        }
      }
  }
}

extern "C" void kernel_launch(void* const* d_in, const int* in_sizes, int n_in,
                              void* d_out, int out_size, void* d_ws, size_t ws_size,
                              hipStream_t stream) {
  const float* x   = (const float*)d_in[0];
  const float* h   = (const float*)d_in[1];
  const float* W   = (const float*)d_in[2];
  const float* W1  = (const float*)d_in[3];
  const float* W2  = (const float*)d_in[4];
  const float* W3  = (const float*)d_in[5];
  const float* U   = (const float*)d_in[6];
  const float* U1  = (const float*)d_in[7];
  const float* U2  = (const float*)d_in[8];
  const float* U3  = (const float*)d_in[9];
  const float* u1d = (const float*)d_in[10];
  const float* u2d = (const float*)d_in[11];
  const float* u3d = (const float*)d_in[12];
  const float* bR  = (const float*)d_in[13];
  const float* bZ  = (const float*)d_in[14];
  const float* bU  = (const float*)d_in[15];
  short* ws = (short*)d_ws;

  prep_kernel<<<2048, 256, 0, stream>>>(W, W1, W2, W3, U, U1, U2, U3, ws);
  gru_fused<<<512, 512, 0, stream>>>(x, h, u1d, u2d, u3d, bR, bZ, bU, ws, (float*)d_out);
}

// Round 4
// 322.367 us; speedup vs baseline: 1.8694x; 1.0498x over previous
//
#include <hip/hip_runtime.h>
#include <hip/hip_bf16.h>

// ---------------------------------------------------------------------------
// myGRUCell low-rank fused monolith, R4: R3 + explicit memory-level
// parallelism (depth-2 rotating prefetch on all global streams, hoisted
// scattered h loads).  Math identical to R3 (absmax 0.0522).
//   grid 512 x 512 threads (8 waves), 2 blocks/CU, 16 waves/CU.
// ws: bf16 weights:
//   [0      ..65535 ] Wt  [64][1024]
//   [65536  ..131071] Ut  [64][1024]
//   [131072 ..262143] P1t [1024][128] (k<64: W1, else U1)
//   [262144 ..393215] P2t [1024][128]
//   [393216 ..524287] P3t [1024][128]
// ---------------------------------------------------------------------------

typedef __attribute__((ext_vector_type(8))) short short8;   // 8 x bf16
typedef __attribute__((ext_vector_type(4))) float f32x4;
typedef __attribute__((ext_vector_type(4))) float f4;

#define WS_UT   65536
#define WS_P1T  131072
#define WS_P2T  262144
#define WS_P3T  393216

__device__ __forceinline__ short f2bf(float f) {
  unsigned u = __builtin_bit_cast(unsigned, f);
  u += 0x7FFFu + ((u >> 16) & 1u);          // round-nearest-even
  return (short)(u >> 16);
}

__device__ __forceinline__ short8 cvt8(f4 a, f4 b) {
  short8 r;
#pragma unroll
  for (int j = 0; j < 4; ++j) { r[j] = f2bf(a[j]); r[4 + j] = f2bf(b[j]); }
  return r;
}

__device__ __forceinline__ f32x4 mfma16(short8 a, short8 b, f32x4 c) {
  return __builtin_amdgcn_mfma_f32_16x16x32_bf16(a, b, c, 0, 0, 0);
}

// XOR-swizzled LDS tiles (16B granule x row&7).
__device__ __forceinline__ short8 rd192(const short* b, int row, int col) {
  return *reinterpret_cast<const short8*>(b + row * 192 + (col ^ ((row & 7) << 3)));
}
__device__ __forceinline__ void wr192(short* b, int row, int col, short v) {
  b[row * 192 + (col ^ ((row & 7) << 3))] = v;
}
__device__ __forceinline__ short8 rd128(const short* b, int row, int col) {
  return *reinterpret_cast<const short8*>(b + row * 128 + (col ^ ((row & 7) << 3)));
}
__device__ __forceinline__ void wr128(short* b, int row, int col, short v) {
  b[row * 128 + (col ^ ((row & 7) << 3))] = v;
}

__device__ __forceinline__ float sigm_f(float v) { return 1.f / (1.f + __expf(-v)); }
__device__ __forceinline__ float tanh_f(float v) { return 1.f - 2.f / (__expf(2.f * v) + 1.f); }

// ---------------------------------------------------------------------------
__global__ void prep_kernel(const float* __restrict__ W,  const float* __restrict__ W1,
                            const float* __restrict__ W2, const float* __restrict__ W3,
                            const float* __restrict__ U,  const float* __restrict__ U1,
                            const float* __restrict__ U2, const float* __restrict__ U3,
                            short* __restrict__ ws) {
  int i = blockIdx.x * blockDim.x + threadIdx.x;  // 0 .. 524287
  float v;
  if (i < 65536) {
    int n = i >> 10, k = i & 1023;
    v = W[k * 64 + n];
  } else if (i < 131072) {
    int j = i - 65536;
    int n = j >> 10, k = j & 1023;
    v = U[k * 64 + n];
  } else {
    int j = i - 131072;
    int sel = j >> 17;          // 0,1,2
    int jj = j & 131071;
    int n = jj >> 7, k = jj & 127;
    const float* Wk = sel == 0 ? W1 : sel == 1 ? W2 : W3;
    const float* Uk = sel == 0 ? U1 : sel == 1 ? U2 : U3;
    v = (k < 64) ? Wk[k * 1024 + n] : Uk[(k - 64) * 1024 + n];
  }
  ws[i] = f2bf(v);
}

// ---------------------------------------------------------------------------
__global__ __launch_bounds__(512, 4) void gru_fused(
    const float* __restrict__ x, const float* __restrict__ h,
    const float* __restrict__ u1d, const float* __restrict__ u2d,
    const float* __restrict__ u3d,
    const float* __restrict__ biasR, const float* __restrict__ biasZ,
    const float* __restrict__ biasU,
    const short* __restrict__ ws, float* __restrict__ out) {
  const short* Wt  = ws;
  const short* Ut  = ws + WS_UT;
  const short* P1t = ws + WS_P1T;
  const short* P2t = ws + WS_P2T;
  const short* P3t = ws + WS_P3T;

  __shared__ __align__(16) short sA[64 * 192];       // [xW | hU | rhU]
  __shared__ __align__(16) short sRH[2][64 * 128];   // rh col-tile, dbuf

  const int tid = threadIdx.x;
  const int w   = tid >> 6;      // wave 0..7
  const int l   = tid & 63;
  const int l15 = l & 15;
  const int lg  = l >> 4;
  const int r0  = blockIdx.x * 64;

  // ---- Phase 0 (no barriers): wave w: rows 16*(w&3); w<4 -> xW, w>=4 -> hU.
  // Depth-2 rotating prefetch on the A stream (x/h) and the 4 B fragments.
  {
    const int g = w & 3;
    const int m = w >> 2;
    const float* srow = (m ? h : x) + (size_t)(r0 + 16 * g + l15) * 1024 + lg * 8;
    const short* Bt0  = (m ? Ut : Wt) + (size_t)l15 * 1024 + lg * 8;
    f32x4 acc[4] = {};

    f4 xa = *reinterpret_cast<const f4*>(srow);
    f4 xb = *reinterpret_cast<const f4*>(srow + 4);
    short8 bw[4];
#pragma unroll
    for (int cf = 0; cf < 4; ++cf)
      bw[cf] = *reinterpret_cast<const short8*>(Bt0 + cf * 16 * 1024);

    for (int k0 = 0; k0 < 1024; k0 += 32) {
      f4 na = xa, nb = xb;
      short8 nw[4] = {bw[0], bw[1], bw[2], bw[3]};
      if (k0 + 32 < 1024) {
        na = *reinterpret_cast<const f4*>(srow + k0 + 32);
        nb = *reinterpret_cast<const f4*>(srow + k0 + 36);
#pragma unroll
        for (int cf = 0; cf < 4; ++cf)
          nw[cf] = *reinterpret_cast<const short8*>(Bt0 + cf * 16 * 1024 + k0 + 32);
      }
      short8 av = cvt8(xa, xb);
#pragma unroll
      for (int cf = 0; cf < 4; ++cf) acc[cf] = mfma16(av, bw[cf], acc[cf]);
      xa = na; xb = nb;
#pragma unroll
      for (int cf = 0; cf < 4; ++cf) bw[cf] = nw[cf];
    }
#pragma unroll
    for (int cf = 0; cf < 4; ++cf)
#pragma unroll
      for (int j = 0; j < 4; ++j)
        wr192(sA, 16 * g + lg * 4 + j, m * 64 + cf * 16 + l15, f2bf(acc[cf][j]));
  }
  __syncthreads();

  const int wr = w >> 2;          // 0,1 : 32-row half
  const int wc = w & 3;           // 0..3: 32-col quarter of the 128-tile
  const int m0 = 32 * wr;
  const int wq = w & 3;           // accU row group
  const int wh = w >> 2;          // accU col half
  const int colw = wc * 32 + l15; // within-tile col base for sRH

  // ---- Phase 1: r -> rh -> rhU accumulation.  1 barrier per tile.
  f32x4 accU[2] = {};
  for (int t = 0; t < 8; ++t) {
    const int n0 = t * 128 + wc * 32;

    // hoisted scattered loads: 16 h values + gate params, issued first
    float hv[2][2][4], d1_[2], br_[2];
#pragma unroll
    for (int cf = 0; cf < 2; ++cf) {
      const int cc = n0 + cf * 16 + l15;
#pragma unroll
      for (int rf = 0; rf < 2; ++rf)
#pragma unroll
        for (int j = 0; j < 4; ++j)
          hv[rf][cf][j] = h[(size_t)(r0 + m0 + rf * 16 + lg * 4 + j) * 1024 + cc];
      d1_[cf] = u1d[cc];
      br_[cf] = biasR[cc];
    }

    // accR GEMM, B depth-2 rotated
    f32x4 accR[2][2] = {};
    {
      const short* P1b = P1t + (size_t)(n0 + l15) * 128 + lg * 8;
      short8 c0 = *reinterpret_cast<const short8*>(P1b);
      short8 c1 = *reinterpret_cast<const short8*>(P1b + 2048);
#pragma unroll
      for (int k0 = 0; k0 < 128; k0 += 32) {
        short8 n0f = c0, n1f = c1;
        if (k0 < 96) {
          n0f = *reinterpret_cast<const short8*>(P1b + k0 + 32);
          n1f = *reinterpret_cast<const short8*>(P1b + 2048 + k0 + 32);
        }
        short8 a0 = rd192(sA, m0 + l15,      k0 + lg * 8);
        short8 a1 = rd192(sA, m0 + 16 + l15, k0 + lg * 8);
        accR[0][0] = mfma16(a0, c0, accR[0][0]);
        accR[1][0] = mfma16(a1, c0, accR[1][0]);
        accR[0][1] = mfma16(a0, c1, accR[0][1]);
        accR[1][1] = mfma16(a1, c1, accR[1][1]);
        c0 = n0f; c1 = n1f;
      }
    }

    short* rhbuf = &sRH[t & 1][0];
#pragma unroll
    for (int rf = 0; rf < 2; ++rf)
#pragma unroll
      for (int cf = 0; cf < 2; ++cf)
#pragma unroll
        for (int j = 0; j < 4; ++j) {
          int rr = m0 + rf * 16 + lg * 4 + j;
          float rv = sigm_f(accR[rf][cf][j] + hv[rf][cf][j] * d1_[cf] + br_[cf]);
          wr128(rhbuf, rr, colw + cf * 16, f2bf(rv * hv[rf][cf][j]));
        }
    __syncthreads();

    // accU GEMM, B depth-2 rotated
    {
      const short* Ub = Ut + (size_t)(wh * 32 + l15) * 1024 + t * 128 + lg * 8;
      short8 c0 = *reinterpret_cast<const short8*>(Ub);
      short8 c1 = *reinterpret_cast<const short8*>(Ub + 16384);
#pragma unroll
      for (int kk = 0; kk < 128; kk += 32) {
        short8 n0f = c0, n1f = c1;
        if (kk < 96) {
          n0f = *reinterpret_cast<const short8*>(Ub + kk + 32);
          n1f = *reinterpret_cast<const short8*>(Ub + 16384 + kk + 32);
        }
        short8 a = rd128(rhbuf, 16 * wq + l15, kk + lg * 8);
        accU[0] = mfma16(a, c0, accU[0]);
        accU[1] = mfma16(a, c1, accU[1]);
        c0 = n0f; c1 = n1f;
      }
    }
  }
  // rhU -> sA cols 128..191
#pragma unroll
  for (int cf = 0; cf < 2; ++cf)
#pragma unroll
    for (int j = 0; j < 4; ++j)
      wr192(sA, 16 * wq + lg * 4 + j, 128 + wh * 32 + cf * 16 + l15, f2bf(accU[cf][j]));
  __syncthreads();

  // ---- Phase 2 (no barriers): recompute r,z; c; gate; store.
  for (int t = 0; t < 8; ++t) {
    const int n0 = t * 128 + wc * 32;

    // hoisted scattered loads first
    float hv[2][2][4], d1_[2], d2_[2], d3_[2], br_[2], bz_[2], bu_[2];
#pragma unroll
    for (int cf = 0; cf < 2; ++cf) {
      const int cc = n0 + cf * 16 + l15;
#pragma unroll
      for (int rf = 0; rf < 2; ++rf)
#pragma unroll
        for (int j = 0; j < 4; ++j)
          hv[rf][cf][j] = h[(size_t)(r0 + m0 + rf * 16 + lg * 4 + j) * 1024 + cc];
      d1_[cf] = u1d[cc]; d2_[cf] = u2d[cc]; d3_[cf] = u3d[cc];
      br_[cf] = biasR[cc]; bz_[cf] = biasZ[cc]; bu_[cf] = biasU[cc];
    }

    f32x4 aR[2][2] = {}, aZ[2][2] = {}, aC[2][2] = {};
#pragma unroll
    for (int cf = 0; cf < 2; ++cf) {
      const size_t bbase = (size_t)(n0 + cf * 16 + l15) * 128 + lg * 8;
      const short* Pb1 = P1t + bbase;
      const short* Pb2 = P2t + bbase;
      const short* Pb3 = P3t + bbase;
      short8 c1 = *reinterpret_cast<const short8*>(Pb1);
      short8 c2 = *reinterpret_cast<const short8*>(Pb2);
      short8 c3 = *reinterpret_cast<const short8*>(Pb3);
#pragma unroll
      for (int k0 = 0; k0 < 128; k0 += 32) {
        short8 m1 = c1, m2 = c2, m3 = c3;
        if (k0 < 96) {
          m1 = *reinterpret_cast<const short8*>(Pb1 + k0 + 32);
          m2 = *reinterpret_cast<const short8*>(Pb2 + k0 + 32);
          m3 = *reinterpret_cast<const short8*>(Pb3 + k0 + 32);
        }
        short8 a12_0 = rd192(sA, m0 + l15,      k0 + lg * 8);
        short8 a12_1 = rd192(sA, m0 + 16 + l15, k0 + lg * 8);
        short8 a3_0, a3_1;
        if (k0 < 64) { a3_0 = a12_0; a3_1 = a12_1; }
        else {
          a3_0 = rd192(sA, m0 + l15,      64 + k0 + lg * 8);   // 128 + (k0-64)
          a3_1 = rd192(sA, m0 + 16 + l15, 64 + k0 + lg * 8);
        }
        aR[0][cf] = mfma16(a12_0, c1, aR[0][cf]);
        aR[1][cf] = mfma16(a12_1, c1, aR[1][cf]);
        aZ[0][cf] = mfma16(a12_0, c2, aZ[0][cf]);
        aZ[1][cf] = mfma16(a12_1, c2, aZ[1][cf]);
        aC[0][cf] = mfma16(a3_0,  c3, aC[0][cf]);
        aC[1][cf] = mfma16(a3_1,  c3, aC[1][cf]);
        c1 = m1; c2 = m2; c3 = m3;
      }
    }

#pragma unroll
    for (int rf = 0; rf < 2; ++rf)
#pragma unroll
      for (int cf = 0; cf < 2; ++cf) {
        const int cc = n0 + cf * 16 + l15;
#pragma unroll
        for (int j = 0; j < 4; ++j) {
          int rr = m0 + rf * 16 + lg * 4 + j;
          size_t gi = (size_t)(r0 + rr) * 1024 + cc;
          float hvj = hv[rf][cf][j];
          float rv = sigm_f(aR[rf][cf][j] + hvj * d1_[cf] + br_[cf]);
          float zv = sigm_f(aZ[rf][cf][j] + hvj * d2_[cf] + bz_[cf]);
          float cv = tanh_f(aC[rf][cf][j] + rv * hvj * d3_[cf] + bu_[cf]);
          out[gi] = zv * hvj + (1.f - zv) * cv;
        }
      }
  }
}

extern "C" void kernel_launch(void* const* d_in, const int* in_sizes, int n_in,
                              void* d_out, int out_size, void* d_ws, size_t ws_size,
                              hipStream_t stream) {
  const float* x   = (const float*)d_in[0];
  const float* h   = (const float*)d_in[1];
  const float* W   = (const float*)d_in[2];
  const float* W1  = (const float*)d_in[3];
  const float* W2  = (const float*)d_in[4];
  const float* W3  = (const float*)d_in[5];
  const float* U   = (const float*)d_in[6];
  const float* U1  = (const float*)d_in[7];
  const float* U2  = (const float*)d_in[8];
  const float* U3  = (const float*)d_in[9];
  const float* u1d = (const float*)d_in[10];
  const float* u2d = (const float*)d_in[11];
  const float* u3d = (const float*)d_in[12];
  const float* bR  = (const float*)d_in[13];
  const float* bZ  = (const float*)d_in[14];
  const float* bU  = (const float*)d_in[15];
  short* ws = (short*)d_ws;

  prep_kernel<<<2048, 256, 0, stream>>>(W, W1, W2, W3, U, U1, U2, U3, ws);
  gru_fused<<<512, 512, 0, stream>>>(x, h, u1d, u2d, u3d, bR, bZ, bU, ws, (float*)d_out);
}